// Round 17
// baseline (263.233 us; speedup 1.0000x reference)
//
#include <hip/hip_runtime.h>
#include <stdint.h>

typedef __attribute__((ext_vector_type(4))) int int32x4;

#define PK_TILE_U32 131072   // one 128-row packed tile = 512 KB = 131072 u32
#define PK_TILE_B   524288

// ---------------------------------------------------------------------------
// sign_pack2: f32 -> i8 (+1/-1), blocked k-major layout:
//   [tile = row/128][chunk = k/16][row % 128][16 bytes]
// Each 64-k slice of a 128-row tile is one LINEAR 8 KB block.
// ---------------------------------------------------------------------------
__global__ __launch_bounds__(256) void sign_pack2(const float* __restrict__ x,
                                                  const float* __restrict__ w,
                                                  uint32_t* __restrict__ xp,
                                                  uint32_t* __restrict__ wp) {
    const float* in = blockIdx.y ? w : x;
    uint32_t* outp  = blockIdx.y ? wp : xp;
    const int lane = threadIdx.x & 63;
    const int wave = (blockIdx.x * blockDim.x + threadIdx.x) >> 6;
    const int nw   = (gridDim.x * blockDim.x) >> 6;
    for (int it = wave; it < 4096 * 16; it += nw) {
        const int row = it >> 4;
        const int col = ((it & 15) << 8) + lane * 4;
        float4 v = *(const float4*)(in + (size_t)row * 4096 + col);
        uint32_t wd = (v.x > 0.f ? 1u : 0xFFu)
                    | ((v.y > 0.f ? 1u : 0xFFu) << 8)
                    | ((v.z > 0.f ? 1u : 0xFFu) << 16)
                    | ((v.w > 0.f ? 1u : 0xFFu) << 24);
        const int tile = row >> 7, rl = row & 127;
        const int chunk = col >> 4;          // k/16
        const int word  = (col >> 2) & 3;    // u32 within 16B slot
        outp[(size_t)tile * PK_TILE_U32 + chunk * 512 + rl * 4 + word] = wd;
    }
}

// ---------------------------------------------------------------------------
// i8 MFMA GEMM v9 — wave tile 128x128 + register-prefetch pipeline.
// R9-R16 post-mortem: all schedules at wave tile 128x64 summed MFMA (34.8us)
// + LDS reads (~29us) because per-phase barriers kept all waves in the same
// phase (reads burst, then MFMA burst). Two levers:
//  (1) wave tile 128x128 (4 waves, 256 thr, 256^2 block): LDS read demand
//      per op HALVES (total 20.5us << MFMA 34.8us).
//  (2) ONE barrier per 64-MFMA window + reg double-buffer: per window g:
//      STAGE(g+2) -> vmcnt(8) -> s_barrier -> ds_read slot g+1 into regNext
//      -> 64 MFMA on regCur (compiler emits counted lgkm for the reg loads,
//      so reads overlap MFMA).
// Hazards (ring 4 x 32 KB, stage lead 2): stage(g+1) landed for ALL waves =
// vmcnt(8) [own 8 oldest done] + barrier. STAGE(g+2) overwrites slot g-2:
// every wave's slot-(g-2) reads completed before ITS window-(g-2) MFMA
// (in-order LDS + compiler lgkm), which precedes the window-(g-1) barrier
// that the staging wave has already passed -> airtight, no second barrier.
// Tail: vmcnt(0) at g>=62; reads skipped at g=63.
// Frag layouts R9/R13-verified exact: A row=lane&15, chunk=lane>>4;
// C/D col=lane&15, row=(lane>>4)*4+reg. Slot: A 16K [rt2][chunk4][row128][16B]
// @0 (rt=wr), B same @16384 (rt=wc). Grid 256 = 1 block/CU, XCD swizzle.
// ---------------------------------------------------------------------------
__device__ __forceinline__ void stage_slot(uint8_t* lds,
                                           const uint8_t* gA, const uint8_t* gB,
                                           int wvo, int s, int boff) {
#define GL9(src, doff) __builtin_amdgcn_global_load_lds( \
        (const __attribute__((address_space(1))) uint32_t*)(src), \
        (__attribute__((address_space(3))) uint32_t*)(lds + (boff) + (doff) + wvo), 16, 0, 0)
    const uint8_t* a0 = gA + (size_t)s * 8192;
    const uint8_t* a1 = gA + PK_TILE_B + (size_t)s * 8192;
    const uint8_t* b0 = gB + (size_t)s * 8192;
    const uint8_t* b1 = gB + PK_TILE_B + (size_t)s * 8192;
    GL9(a0,        0);  GL9(a0 + 4096,  4096);
    GL9(a1,     8192);  GL9(a1 + 4096, 12288);
    GL9(b0,    16384);  GL9(b0 + 4096, 20480);
    GL9(b1,    24576);  GL9(b1 + 4096, 28672);
#undef GL9
}

__global__ __launch_bounds__(256) void i8_gemm9(const uint32_t* __restrict__ xp,
                                                const uint32_t* __restrict__ wp,
                                                float* __restrict__ out) {
    __shared__ uint4 ldsv[8192];   // 128 KB = 4 slots x 32 KB
    uint8_t* lds = (uint8_t*)ldsv;

    const int tid  = threadIdx.x;
    const int lane = tid & 63;
    const int wv   = tid >> 6;     // 0..3
    const int wr   = wv >> 1;      // row half (128 rows)
    const int wc   = wv & 1;       // col half (128 cols)

    int lid = blockIdx.x;          // bijective XCD swizzle (256 % 8 == 0)
    lid = (lid & 7) * 32 + (lid >> 3);
    const int brow = lid >> 4, bcol = lid & 15;

    const uint8_t* gA = (const uint8_t*)(xp + (size_t)(brow * 2) * PK_TILE_U32) + tid * 16;
    const uint8_t* gB = (const uint8_t*)(wp + (size_t)(bcol * 2) * PK_TILE_U32) + tid * 16;
    const int wvo = wv * 1024;

    int32x4 acc[8][8];
#pragma unroll
    for (int m = 0; m < 8; ++m)
#pragma unroll
        for (int n = 0; n < 8; ++n) acc[m][n] = (int32x4){0, 0, 0, 0};

    const int paBase = wr * 8192 + (lane >> 4) * 2048 + (lane & 15) * 16;
    const int pbBase = 16384 + wc * 8192 + (lane >> 4) * 2048 + (lane & 15) * 16;

    int32x4 aC[8], bC[8], aN[8], bN[8];

    // prologue: stage slots 0,1; wait slot 0; load its frags
    stage_slot(lds, gA, gB, wvo, 0, 0);
    stage_slot(lds, gA, gB, wvo, 1, 32768);
    asm volatile("s_waitcnt vmcnt(8)" ::: "memory");
    __builtin_amdgcn_s_barrier();
    __builtin_amdgcn_sched_barrier(0);
#pragma unroll
    for (int m = 0; m < 8; ++m) aC[m] = *(const int32x4*)(lds + paBase + m * 256);
#pragma unroll
    for (int n = 0; n < 8; ++n) bC[n] = *(const int32x4*)(lds + pbBase + n * 256);

#define WINDOW(CA, CB, NA, NB, g) do {                                        \
        if ((g) + 2 < 64) stage_slot(lds, gA, gB, wvo, (g) + 2,               \
                                     (((g) + 2) & 3) * 32768);                \
        if ((g) < 62) asm volatile("s_waitcnt vmcnt(8)" ::: "memory");        \
        else          asm volatile("s_waitcnt vmcnt(0)" ::: "memory");        \
        __builtin_amdgcn_s_barrier();                                         \
        __builtin_amdgcn_sched_barrier(0);                                    \
        if ((g) + 1 < 64) {                                                   \
            const int ro = (((g) + 1) & 3) * 32768;                           \
            _Pragma("unroll")                                                 \
            for (int m = 0; m < 8; ++m)                                       \
                NA[m] = *(const int32x4*)(lds + ro + paBase + m * 256);       \
            _Pragma("unroll")                                                 \
            for (int n = 0; n < 8; ++n)                                       \
                NB[n] = *(const int32x4*)(lds + ro + pbBase + n * 256);       \
        }                                                                     \
        __builtin_amdgcn_s_setprio(1);                                        \
        _Pragma("unroll")                                                     \
        for (int m = 0; m < 8; ++m)                                           \
            _Pragma("unroll")                                                 \
            for (int n = 0; n < 8; ++n)                                       \
                acc[m][n] = __builtin_amdgcn_mfma_i32_16x16x64_i8(            \
                    CA[m], CB[n], acc[m][n], 0, 0, 0);                        \
        __builtin_amdgcn_s_setprio(0);                                        \
    } while (0)

#pragma unroll 1
    for (int g = 0; g < 64; g += 2) {
        WINDOW(aC, bC, aN, bN, g);
        WINDOW(aN, bN, aC, bC, g + 1);
    }
#undef WINDOW

    // epilogue: i32 -> f32 exact. C/D: col = lane&15, row = (lane>>4)*4 + reg
    const int orow = brow * 256 + wr * 128 + (lane >> 4) * 4;
    const int ocol = bcol * 256 + wc * 128 + (lane & 15);
#pragma unroll
    for (int m = 0; m < 8; ++m)
#pragma unroll
        for (int reg = 0; reg < 4; ++reg) {
            const size_t rb = (size_t)(orow + m * 16 + reg) * 4096 + ocol;
#pragma unroll
            for (int n = 0; n < 8; ++n)
                out[rb + n * 16] = (float)acc[m][n][reg];
        }
}

// ======================= fallback (R8 binary path) =========================
__global__ __launch_bounds__(256) void binarize64(const float* __restrict__ in,
                                                  unsigned long long* __restrict__ out,
                                                  int n64) {
    const int tid  = blockIdx.x * blockDim.x + threadIdx.x;
    const int lane = threadIdx.x & 63;
    const int wave = tid >> 6;
    const int nwav = (gridDim.x * blockDim.x) >> 6;
    for (int w = wave; w < n64; w += nwav) {
        float v = in[(size_t)w * 64 + lane];
        unsigned long long m = __ballot(v > 0.0f);
        if (lane == 0) out[w] = m;
    }
}

static __device__ __forceinline__ void pacc4(uint32_t& acc, const uint4& a, const uint4& b) {
    uint32_t t0, t1, t2, t3;
    asm("v_xor_b32 %1, %5, %9\n\t"
        "v_xor_b32 %2, %6, %10\n\t"
        "v_xor_b32 %3, %7, %11\n\t"
        "v_xor_b32 %4, %8, %12\n\t"
        "v_bcnt_u32_b32 %0, %1, %0\n\t"
        "v_bcnt_u32_b32 %0, %2, %0\n\t"
        "v_bcnt_u32_b32 %0, %3, %0\n\t"
        "v_bcnt_u32_b32 %0, %4, %0"
        : "+v"(acc), "=&v"(t0), "=&v"(t1), "=&v"(t2), "=&v"(t3)
        : "v"(a.x), "v"(a.y), "v"(a.z), "v"(a.w),
          "v"(b.x), "v"(b.y), "v"(b.z), "v"(b.w));
}

__global__ __launch_bounds__(256, 2) void xnor_gemm(const uint32_t* __restrict__ xb,
                                                    const uint32_t* __restrict__ wb,
                                                    float* __restrict__ out) {
    __shared__ uint4 lA[128 * 8];
    __shared__ uint4 lB[64 * 8];
    const int tid  = threadIdx.x;
    const int brow = blockIdx.y, bcol = blockIdx.x;
    const int tx = tid & 15, ty = tid >> 4;
    const uint4* gA = (const uint4*)xb + (size_t)(brow * 128) * 32;
    const uint4* gB = (const uint4*)wb + (size_t)(bcol * 64) * 32;
    const int sr = tid >> 3, scw = tid & 7;
    uint32_t acc[8][4];
#pragma unroll
    for (int r = 0; r < 8; ++r)
#pragma unroll
        for (int c = 0; c < 4; ++c) acc[r][c] = 0;
    const uint4* pa = lA + ty * 64;
    const uint4* pb = lB + tx * 32;
    const int ka = ty & 7, kb = tx >> 1;
    for (int ck = 0; ck < 4; ++ck) {
        if (ck) __syncthreads();
#pragma unroll
        for (int k = 0; k < 4; ++k) {
            const int r = sr + k * 32;
            lA[r * 8 + (scw ^ ((r >> 3) & 7))] = gA[(size_t)r * 32 + ck * 8 + scw];
        }
#pragma unroll
        for (int k = 0; k < 2; ++k) {
            const int r = sr + k * 32;
            lB[r * 8 + (scw ^ ((r >> 3) & 7))] = gB[(size_t)r * 32 + ck * 8 + scw];
        }
        __syncthreads();
#pragma unroll 1
        for (int j = 0; j < 8; ++j) {
            const uint4* paj = pa + (j ^ ka);
            const uint4* pbj = pb + (j ^ kb);
            uint4 a[8], b[4];
#pragma unroll
            for (int r = 0; r < 8; ++r) a[r] = paj[r * 8];
#pragma unroll
            for (int c = 0; c < 4; ++c) b[c] = pbj[c * 8];
#pragma unroll
            for (int r = 0; r < 8; ++r)
#pragma unroll
                for (int c = 0; c < 4; ++c) pacc4(acc[r][c], a[r], b[c]);
        }
    }
    const int gcol = bcol * 64 + tx * 4;
#pragma unroll
    for (int r = 0; r < 8; ++r) {
        const size_t grow = (size_t)(brow * 128 + ty * 8 + r);
        float4 o;
        o.x = (float)(4096 - 2 * (int)acc[r][0]);
        o.y = (float)(4096 - 2 * (int)acc[r][1]);
        o.z = (float)(4096 - 2 * (int)acc[r][2]);
        o.w = (float)(4096 - 2 * (int)acc[r][3]);
        *(float4*)(out + grow * 4096 + gcol) = o;
    }
}

extern "C" void kernel_launch(void* const* d_in, const int* in_sizes, int n_in,
                              void* d_out, int out_size, void* d_ws, size_t ws_size,
                              hipStream_t stream) {
    const float* x = (const float*)d_in[0];   // [4096, 4096]
    const float* W = (const float*)d_in[1];   // [4096, 4096] (out, in)
    float* out = (float*)d_out;               // [4096, 4096] f32

    if (ws_size >= 2u * 16777216u) {
        uint32_t* xp = (uint32_t*)d_ws;                 // 16 MB packed x
        uint32_t* wpk = xp + (size_t)4194304;           // 16 MB packed W
        sign_pack2<<<dim3(2048, 2), 256, 0, stream>>>(x, W, xp, wpk);
        i8_gemm9<<<256, 256, 0, stream>>>(xp, wpk, out);
    } else {
        uint32_t* xb = (uint32_t*)d_ws;
        uint32_t* wb = xb + (size_t)4096 * 128;
        const int n64 = 4096 * 4096 / 64;
        binarize64<<<2048, 256, 0, stream>>>(x, (unsigned long long*)xb, n64);
        binarize64<<<2048, 256, 0, stream>>>(W, (unsigned long long*)wb, n64);
        dim3 grid(64, 32);
        xnor_gemm<<<grid, 256, 0, stream>>>(xb, wb, out);
    }
}

// Round 18
// 105.125 us; speedup vs baseline: 2.5040x; 2.5040x over previous
//
#include <hip/hip_runtime.h>
#include <stdint.h>

typedef __attribute__((ext_vector_type(4)))  int int32x4;
typedef __attribute__((ext_vector_type(16))) int int32x16;

#define PK_TILE_U32 131072   // one 128-row packed tile = 512 KB = 131072 u32

// ---------------------------------------------------------------------------
// sign_pack2: f32 -> i8 (+1/-1), blocked k-major layout:
//   [tile = row/128][chunk = k/16][row % 128][16 bytes]
// Each 128-k K-tile of a 128-row tile is one LINEAR 16 KB block.
// ---------------------------------------------------------------------------
__global__ __launch_bounds__(256) void sign_pack2(const float* __restrict__ x,
                                                  const float* __restrict__ w,
                                                  uint32_t* __restrict__ xp,
                                                  uint32_t* __restrict__ wp) {
    const float* in = blockIdx.y ? w : x;
    uint32_t* outp  = blockIdx.y ? wp : xp;
    const int lane = threadIdx.x & 63;
    const int wave = (blockIdx.x * blockDim.x + threadIdx.x) >> 6;
    const int nw   = (gridDim.x * blockDim.x) >> 6;
    for (int it = wave; it < 4096 * 16; it += nw) {
        const int row = it >> 4;
        const int col = ((it & 15) << 8) + lane * 4;
        float4 v = *(const float4*)(in + (size_t)row * 4096 + col);
        uint32_t wd = (v.x > 0.f ? 1u : 0xFFu)
                    | ((v.y > 0.f ? 1u : 0xFFu) << 8)
                    | ((v.z > 0.f ? 1u : 0xFFu) << 16)
                    | ((v.w > 0.f ? 1u : 0xFFu) << 24);
        const int tile = row >> 7, rl = row & 127;
        const int chunk = col >> 4;          // k/16
        const int word  = (col >> 2) & 3;    // u32 within 16B slot
        outp[(size_t)tile * PK_TILE_U32 + chunk * 512 + rl * 4 + word] = wd;
    }
}

// ---------------------------------------------------------------------------
// i8 MFMA GEMM v10 — R13 structure, 32x32x32 MFMA (HALF the instructions).
// R9-R16 invariant: every schedule at wave tile 128x64 with 16x16x64 MFMA
// (16384 inst/CU) lands at 69-78 us, ~39% util — including R9's independent
// 4-blocks/CU (antiphase available, still no overlap). Untested hypothesis:
// per-MFMA-instruction overhead in a mixed stream makes the kernel
// MFMA-INSTRUCTION-bound. mfma_i32_32x32x32_i8 keeps ops and LDS traffic
// identical but halves inst count (8192/CU) and has a 12% higher measured
// ceiling (4404 vs 3944 TOPS, m55/m16).
// Geometry = R13 byte-identical: 256x256 tile, 512 thr = 8 waves (2Mx4N),
// wave tile 128x64 = 4x2 tiles of 32x32; acc[4][2] x int32x16 = 128 AGPR.
// K-tile 128k; LDS 2 x 64 KB dbuf; grid 256 = 1 block/CU; XCD swizzle.
// Frag addressing (blocked k-major [chunk k/16][row][16B]):
//   A lane: row = lane&31 (+m*32), chunk = 2*kk + (lane>>5)
//     -> paBase + kk*4096 + m*512  (32 lanes x 16B = 512B contig, 2-way free)
//   B lane: col row = (wc&1)*64 + n*32 + (lane&31), rt = wc>>1, same chunking
// C/D (guide-verified 32x32, dtype-indep): col = lane&31,
//   row = (reg&3) + 8*(reg>>2) + 4*(lane>>5).
// Schedule = R13's: STAGE(kt+1) first, one __syncthreads per K-tile.
// ---------------------------------------------------------------------------
__global__ __launch_bounds__(512) void i8_gemm10(const uint32_t* __restrict__ xp,
                                                 const uint32_t* __restrict__ wp,
                                                 float* __restrict__ out) {
    __shared__ uint4 ldsv[8192];   // 128 KB: buf0 @0, buf1 @65536; A @+0, B @+32768
    uint8_t* lds = (uint8_t*)ldsv;

    const int tid  = threadIdx.x;
    const int lane = tid & 63;
    const int wv   = tid >> 6;           // 0..7
    const int wr   = wv >> 2;            // row half (128 rows)
    const int wc   = wv & 3;             // col quarter (64 cols)

    int lid = blockIdx.x;                // bijective XCD swizzle (256%8==0)
    lid = (lid & 7) * 32 + (lid >> 3);
    const int brow = lid >> 4, bcol = lid & 15;

    const uint8_t* gA = (const uint8_t*)(xp + (size_t)(brow * 2) * PK_TILE_U32) + tid * 16;
    const uint8_t* gB = (const uint8_t*)(wp + (size_t)(bcol * 2) * PK_TILE_U32) + tid * 16;
    const int wvo = wv * 1024;

#define GL(src, doff) __builtin_amdgcn_global_load_lds( \
        (const __attribute__((address_space(1))) uint32_t*)(src), \
        (__attribute__((address_space(3))) uint32_t*)(lds + (doff) + wvo), 16, 0, 0)

#define STAGE(kt, boff) do {                                          \
        const uint8_t* a_ = gA + (size_t)(kt) * 16384;                \
        const uint8_t* b_ = gB + (size_t)(kt) * 16384;                \
        GL(a_,                    (boff) +     0);                    \
        GL(a_ + 8192,             (boff) +  8192);                    \
        GL(a_ + 524288,           (boff) + 16384);                    \
        GL(a_ + 524288 + 8192,    (boff) + 24576);                    \
        GL(b_,                    (boff) + 32768);                    \
        GL(b_ + 8192,             (boff) + 40960);                    \
        GL(b_ + 524288,           (boff) + 49152);                    \
        GL(b_ + 524288 + 8192,    (boff) + 57344);                    \
    } while (0)

    int32x16 acc[4][2];
#pragma unroll
    for (int m = 0; m < 4; ++m)
#pragma unroll
        for (int n = 0; n < 2; ++n)
#pragma unroll
            for (int r = 0; r < 16; ++r) acc[m][n][r] = 0;

    // frag bases (see header): chunk stride 2048, kk stride 4096, tile stride 512
    const int paBase = wr * 16384 + (lane >> 5) * 2048 + (lane & 31) * 16;
    const int pbBase = 32768 + (wc >> 1) * 16384 + (lane >> 5) * 2048
                     + ((wc & 1) * 64 + (lane & 31)) * 16;

    STAGE(0, 0);
    __syncthreads();

#pragma unroll 1
    for (int kt = 0; kt < 32; ++kt) {
        const int bo = (kt & 1) << 16;
        if (kt + 1 < 32) STAGE(kt + 1, bo ^ 65536);   // issue first: max cover

#pragma unroll
        for (int kk = 0; kk < 4; ++kk) {
            int32x4 a[4], b[2];
#pragma unroll
            for (int m = 0; m < 4; ++m)
                a[m] = *(const int32x4*)(lds + bo + paBase + kk * 4096 + m * 512);
#pragma unroll
            for (int n = 0; n < 2; ++n)
                b[n] = *(const int32x4*)(lds + bo + pbBase + kk * 4096 + n * 512);
#pragma unroll
            for (int m = 0; m < 4; ++m)
#pragma unroll
                for (int n = 0; n < 2; ++n)
                    acc[m][n] = __builtin_amdgcn_mfma_i32_32x32x32_i8(
                        a[m], b[n], acc[m][n], 0, 0, 0);
        }
        __syncthreads();   // one drain per K-tile (R13-proven)
    }

    // epilogue: i32 -> f32 exact.
    // C/D 32x32: col = lane&31, row = (reg&3) + 8*(reg>>2) + 4*(lane>>5)
    const int orow = brow * 256 + wr * 128;
    const int ocol = bcol * 256 + wc * 64 + (lane & 31);
    const int rhi  = 4 * (lane >> 5);
#pragma unroll
    for (int m = 0; m < 4; ++m)
#pragma unroll
        for (int n = 0; n < 2; ++n)
#pragma unroll
            for (int reg = 0; reg < 16; ++reg) {
                const int row = orow + m * 32 + (reg & 3) + 8 * (reg >> 2) + rhi;
                out[(size_t)row * 4096 + ocol + n * 32] = (float)acc[m][n][reg];
            }
#undef STAGE
#undef GL
}

// ======================= fallback (R8 binary path) =========================
__global__ __launch_bounds__(256) void binarize64(const float* __restrict__ in,
                                                  unsigned long long* __restrict__ out,
                                                  int n64) {
    const int tid  = blockIdx.x * blockDim.x + threadIdx.x;
    const int lane = threadIdx.x & 63;
    const int wave = tid >> 6;
    const int nwav = (gridDim.x * blockDim.x) >> 6;
    for (int w = wave; w < n64; w += nwav) {
        float v = in[(size_t)w * 64 + lane];
        unsigned long long m = __ballot(v > 0.0f);
        if (lane == 0) out[w] = m;
    }
}

static __device__ __forceinline__ void pacc4(uint32_t& acc, const uint4& a, const uint4& b) {
    uint32_t t0, t1, t2, t3;
    asm("v_xor_b32 %1, %5, %9\n\t"
        "v_xor_b32 %2, %6, %10\n\t"
        "v_xor_b32 %3, %7, %11\n\t"
        "v_xor_b32 %4, %8, %12\n\t"
        "v_bcnt_u32_b32 %0, %1, %0\n\t"
        "v_bcnt_u32_b32 %0, %2, %0\n\t"
        "v_bcnt_u32_b32 %0, %3, %0\n\t"
        "v_bcnt_u32_b32 %0, %4, %0"
        : "+v"(acc), "=&v"(t0), "=&v"(t1), "=&v"(t2), "=&v"(t3)
        : "v"(a.x), "v"(a.y), "v"(a.z), "v"(a.w),
          "v"(b.x), "v"(b.y), "v"(b.z), "v"(b.w));
}

__global__ __launch_bounds__(256, 2) void xnor_gemm(const uint32_t* __restrict__ xb,
                                                    const uint32_t* __restrict__ wb,
                                                    float* __restrict__ out) {
    __shared__ uint4 lA[128 * 8];
    __shared__ uint4 lB[64 * 8];
    const int tid  = threadIdx.x;
    const int brow = blockIdx.y, bcol = blockIdx.x;
    const int tx = tid & 15, ty = tid >> 4;
    const uint4* gA = (const uint4*)xb + (size_t)(brow * 128) * 32;
    const uint4* gB = (const uint4*)wb + (size_t)(bcol * 64) * 32;
    const int sr = tid >> 3, scw = tid & 7;
    uint32_t acc[8][4];
#pragma unroll
    for (int r = 0; r < 8; ++r)
#pragma unroll
        for (int c = 0; c < 4; ++c) acc[r][c] = 0;
    const uint4* pa = lA + ty * 64;
    const uint4* pb = lB + tx * 32;
    const int ka = ty & 7, kb = tx >> 1;
    for (int ck = 0; ck < 4; ++ck) {
        if (ck) __syncthreads();
#pragma unroll
        for (int k = 0; k < 4; ++k) {
            const int r = sr + k * 32;
            lA[r * 8 + (scw ^ ((r >> 3) & 7))] = gA[(size_t)r * 32 + ck * 8 + scw];
        }
#pragma unroll
        for (int k = 0; k < 2; ++k) {
            const int r = sr + k * 32;
            lB[r * 8 + (scw ^ ((r >> 3) & 7))] = gB[(size_t)r * 32 + ck * 8 + scw];
        }
        __syncthreads();
#pragma unroll 1
        for (int j = 0; j < 8; ++j) {
            const uint4* paj = pa + (j ^ ka);
            const uint4* pbj = pb + (j ^ kb);
            uint4 a[8], b[4];
#pragma unroll
            for (int r = 0; r < 8; ++r) a[r] = paj[r * 8];
#pragma unroll
            for (int c = 0; c < 4; ++c) b[c] = pbj[c * 8];
#pragma unroll
            for (int r = 0; r < 8; ++r)
#pragma unroll
                for (int c = 0; c < 4; ++c) pacc4(acc[r][c], a[r], b[c]);
        }
    }
    const int gcol = bcol * 64 + tx * 4;
#pragma unroll
    for (int r = 0; r < 8; ++r) {
        const size_t grow = (size_t)(brow * 128 + ty * 8 + r);
        float4 o;
        o.x = (float)(4096 - 2 * (int)acc[r][0]);
        o.y = (float)(4096 - 2 * (int)acc[r][1]);
        o.z = (float)(4096 - 2 * (int)acc[r][2]);
        o.w = (float)(4096 - 2 * (int)acc[r][3]);
        *(float4*)(out + grow * 4096 + gcol) = o;
    }
}

extern "C" void kernel_launch(void* const* d_in, const int* in_sizes, int n_in,
                              void* d_out, int out_size, void* d_ws, size_t ws_size,
                              hipStream_t stream) {
    const float* x = (const float*)d_in[0];   // [4096, 4096]
    const float* W = (const float*)d_in[1];   // [4096, 4096] (out, in)
    float* out = (float*)d_out;               // [4096, 4096] f32

    if (ws_size >= 2u * 16777216u) {
        uint32_t* xp = (uint32_t*)d_ws;                 // 16 MB packed x
        uint32_t* wpk = xp + (size_t)4194304;           // 16 MB packed W
        sign_pack2<<<dim3(2048, 2), 256, 0, stream>>>(x, W, xp, wpk);
        i8_gemm10<<<256, 512, 0, stream>>>(xp, wpk, out);
    } else {
        uint32_t* xb = (uint32_t*)d_ws;
        uint32_t* wb = xb + (size_t)4096 * 128;
        const int n64 = 4096 * 4096 / 64;
        binarize64<<<2048, 256, 0, stream>>>(x, (unsigned long long*)xb, n64);
        binarize64<<<2048, 256, 0, stream>>>(W, (unsigned long long*)wb, n64);
        dim3 grid(64, 32);
        xnor_gemm<<<grid, 256, 0, stream>>>(xb, wb, out);
    }
}